// Round 11
// baseline (202.394 us; speedup 1.0000x reference)
//
#include <hip/hip_runtime.h>
#include <hip/hip_bf16.h>
#include <stdint.h>

// MultiGraphConvLayer: H=3 heads, L=2 layers, B=16, S=512, D=512.
// Round 11: MX-scaled fp8 GEMM core (mfma_scale_f32_16x16x128_f8f6f4,
// unit E8M0 scales = exact fp8 math, 2.28x MFMA rate). 128^2 tile,
// BK=128, 2x32KB LDS double buffer, one barrier/step, slot^(r&7) swizzle.
// Scales as R9/R10: y,w x64; axpx x2. Prep/redF unchanged.

#define HH 3
#define LL 2
#define BB 16
#define SS 512
#define DD 512
#define FF 3072  // HH*LL*DD

typedef __attribute__((ext_vector_type(8))) short bf16x8;
typedef __attribute__((ext_vector_type(4))) float f32x4;
typedef __attribute__((ext_vector_type(4))) float vfloat4;
typedef __attribute__((ext_vector_type(4))) short shortx4;
typedef __attribute__((ext_vector_type(2))) unsigned int uint2v;
typedef __attribute__((ext_vector_type(8))) int i32x8;
typedef __attribute__((ext_vector_type(4))) int i32x4;

__device__ __forceinline__ short f2b(float x) {
  union { float f; uint32_t u; } v; v.f = x;
  return (short)((v.u + 0x7FFFu + ((v.u >> 16) & 1u)) >> 16);
}
__device__ __forceinline__ float b2f(short s) {
  union { uint32_t u; float f; } v; v.u = ((uint32_t)(uint16_t)s) << 16;
  return v.f;
}
__device__ __forceinline__ float c8(uint8_t b) {
  return __builtin_amdgcn_cvt_f32_fp8((int)b, 0);
}

__device__ __forceinline__ void gld16b(const uint8_t* g, uint8_t* l) {
  __builtin_amdgcn_global_load_lds((const __attribute__((address_space(1))) void*)g,
                                   (__attribute__((address_space(3))) void*)l, 16, 0, 0);
}

// T1: XCD-chunked blockIdx swizzle (grid divisible by 8 — all ours are).
__device__ __forceinline__ int xswz(int grid) {
  int cpx = grid >> 3;
  return (blockIdx.x & 7) * cpx + (blockIdx.x >> 3);
}

// ---- merged prep: [0,6144) adj->fp8 + rden; [6144,6912) W->fp8 x64;
//      [6912,7936) x0 -> X0T fp8 + x0b bf16.
__global__ void k_prep(const float* __restrict__ adj, uint8_t* __restrict__ adjf8,
                       float* __restrict__ rden,
                       const float* __restrict__ wg, const float* __restrict__ wo,
                       uint8_t* __restrict__ wgb, uint8_t* __restrict__ wob,
                       const float* __restrict__ x, uint8_t* __restrict__ xt,
                       short* __restrict__ x0b) {
  __shared__ short t[64][72];
  int bid = blockIdx.x;
  int tid = threadIdx.x;
  if (bid < 6144) {
    int row = bid * 4 + (tid >> 6);
    int lane = tid & 63;
    const float* src = adj + (size_t)row * SS;
    vfloat4 a = *(const vfloat4*)(src + lane * 8);
    vfloat4 b = *(const vfloat4*)(src + lane * 8 + 4);
    uint32_t w0 = 0, w1 = 0;
    w0 = __builtin_amdgcn_cvt_pk_fp8_f32(a[0], a[1], w0, false);
    w0 = __builtin_amdgcn_cvt_pk_fp8_f32(a[2], a[3], w0, true);
    w1 = __builtin_amdgcn_cvt_pk_fp8_f32(b[0], b[1], w1, false);
    w1 = __builtin_amdgcn_cvt_pk_fp8_f32(b[2], b[3], w1, true);
    uint2v o; o[0] = w0; o[1] = w1;
    *(uint2v*)(adjf8 + (size_t)row * SS + lane * 8) = o;
    float s = a[0]+a[1]+a[2]+a[3]+b[0]+b[1]+b[2]+b[3];
    #pragma unroll
    for (int off = 32; off > 0; off >>= 1) s += __shfl_xor(s, off);
    if (lane == 0) rden[row] = 1.0f / (s + 1.0f);
  } else if (bid < 6912) {
    size_t i = ((size_t)(bid - 6144) * 256 + tid) * 8;
    vfloat4 a = *(const vfloat4*)(wg + i);
    vfloat4 b = *(const vfloat4*)(wg + i + 4);
    uint32_t w0 = 0, w1 = 0;
    w0 = __builtin_amdgcn_cvt_pk_fp8_f32(a[0]*64.f, a[1]*64.f, w0, false);
    w0 = __builtin_amdgcn_cvt_pk_fp8_f32(a[2]*64.f, a[3]*64.f, w0, true);
    w1 = __builtin_amdgcn_cvt_pk_fp8_f32(b[0]*64.f, b[1]*64.f, w1, false);
    w1 = __builtin_amdgcn_cvt_pk_fp8_f32(b[2]*64.f, b[3]*64.f, w1, true);
    uint2v o; o[0] = w0; o[1] = w1;
    *(uint2v*)(wgb + i) = o;
    a = *(const vfloat4*)(wo + i);
    b = *(const vfloat4*)(wo + i + 4);
    w0 = 0; w1 = 0;
    w0 = __builtin_amdgcn_cvt_pk_fp8_f32(a[0]*64.f, a[1]*64.f, w0, false);
    w0 = __builtin_amdgcn_cvt_pk_fp8_f32(a[2]*64.f, a[3]*64.f, w0, true);
    w1 = __builtin_amdgcn_cvt_pk_fp8_f32(b[0]*64.f, b[1]*64.f, w1, false);
    w1 = __builtin_amdgcn_cvt_pk_fp8_f32(b[2]*64.f, b[3]*64.f, w1, true);
    o[0] = w0; o[1] = w1;
    *(uint2v*)(wob + i) = o;
  } else {
    int bid2 = bid - 6912;           // BB*64
    int b = bid2 >> 6, q = bid2 & 63;
    int s0 = (q >> 3) * 64, d0 = (q & 7) * 64;
    int r = tid >> 4, c4 = (tid & 15) * 4;
    const float* src = x + ((size_t)b * SS + s0) * DD + d0;
    #pragma unroll
    for (int rr = 0; rr < 64; rr += 16) {
      vfloat4 v = *(const vfloat4*)(src + (size_t)(r + rr) * DD + c4);
      shortx4 o4;
      o4[0] = f2b(v[0]); o4[1] = f2b(v[1]); o4[2] = f2b(v[2]); o4[3] = f2b(v[3]);
      t[r+rr][c4+0] = o4[0]; t[r+rr][c4+1] = o4[1];
      t[r+rr][c4+2] = o4[2]; t[r+rr][c4+3] = o4[3];
      *(shortx4*)(x0b + ((size_t)b * SS + s0 + r + rr) * DD + d0 + c4) = o4;
    }
    __syncthreads();
    int dloc = tid >> 3, s8 = (tid & 7) * 8;
    uint8_t* dst = xt + (size_t)b * DD * SS + s0;
    #pragma unroll
    for (int dd = 0; dd < 64; dd += 32) {
      float f[8];
      #pragma unroll
      for (int j = 0; j < 8; j++) f[j] = b2f(t[s8 + j][dloc + dd]);
      uint32_t w0 = 0, w1 = 0;
      w0 = __builtin_amdgcn_cvt_pk_fp8_f32(f[0], f[1], w0, false);
      w0 = __builtin_amdgcn_cvt_pk_fp8_f32(f[2], f[3], w0, true);
      w1 = __builtin_amdgcn_cvt_pk_fp8_f32(f[4], f[5], w1, false);
      w1 = __builtin_amdgcn_cvt_pk_fp8_f32(f[6], f[7], w1, true);
      uint2v o; o[0] = w0; o[1] = w1;
      *(uint2v*)(dst + (size_t)(d0 + dloc + dd) * SS + s8) = o;
    }
  }
}

// ========================= MX fp8 GEMM core (K=128 steps) =========================
// C(128x128) = A(128xK fp8, lda bytes) * B'(128xK fp8, ldb)^T.
// mfma_scale_f32_16x16x128_f8f6f4, unit E8M0 scales (0x7F = 2^0) -> exact fp8.
// 4 waves, 64x64 each; per-wave 4x4 16x16 frags (C/D layout = 16x16 family,
// shape-determined -> epilogues identical to the 16x16x32 core).
// A-frag: row = lane&15, k-bytes = (lane>>4)*32 .. +31 (two b128 reads).
// LDS: 2 bufs x (A 16KB | B 16KB) = 64KB -> 2 blocks/CU. Tile [128 rows][128B],
// 16B slot s of row r holds global slot s^(r&7) (involution; 2-way banks,
// stage keeps 128B/row coalescing; r&7 invariant under +32-row staging step).
// One {vmcnt(0)+lgkm(0), barrier, sched_barrier} per step; stage of tile t+1
// issued after the barrier (all reads of its buffer drained before it).
__device__ __forceinline__ void compute128(const uint8_t* As, const uint8_t* Bs,
                                           int wr, int wc, int lr, int lk,
                                           f32x4 acc[4][4]) {
  i32x8 af[4], bv[4];
  #pragma unroll
  for (int m = 0; m < 4; m++) {
    int r = wr*64 + m*16 + lr;
    const uint8_t* base = As + (size_t)r * 128;
    int x = r & 7;
    i32x4 lo = *(const i32x4*)(base + (((2*lk)     ^ x) << 4));
    i32x4 hi = *(const i32x4*)(base + (((2*lk + 1) ^ x) << 4));
    af[m] = (i32x8){lo[0], lo[1], lo[2], lo[3], hi[0], hi[1], hi[2], hi[3]};
  }
  #pragma unroll
  for (int n = 0; n < 4; n++) {
    int r = wc*64 + n*16 + lr;
    const uint8_t* base = Bs + (size_t)r * 128;
    int x = r & 7;
    i32x4 lo = *(const i32x4*)(base + (((2*lk)     ^ x) << 4));
    i32x4 hi = *(const i32x4*)(base + (((2*lk + 1) ^ x) << 4));
    bv[n] = (i32x8){lo[0], lo[1], lo[2], lo[3], hi[0], hi[1], hi[2], hi[3]};
  }
  #pragma unroll
  for (int m = 0; m < 4; m++)
    #pragma unroll
    for (int n = 0; n < 4; n++)
      acc[m][n] = __builtin_amdgcn_mfma_scale_f32_16x16x128_f8f6f4(
          af[m], bv[n], acc[m][n], 0 /*cbsz: fp8*/, 0 /*blgp: fp8*/,
          0, 0x7F /*scaleA = 2^0*/, 0, 0x7F /*scaleB = 2^0*/);
}

__device__ __forceinline__ void gemmx8(const uint8_t* __restrict__ A, int lda,
                                       const uint8_t* __restrict__ Bm, int ldb,
                                       int K, uint8_t* lds, f32x4 acc[4][4]) {
  int tid = threadIdx.x;
  int lane = tid & 63, wid = tid >> 6;
  int wr = wid >> 1, wc = wid & 1;
  int lr = lane & 15, lk = lane >> 4;
  int sr = tid >> 3, ss = tid & 7;          // staging: row sr(+32i), slot ss
  int scol = ((ss ^ (sr & 7)) << 4);        // source slot permutation
  const uint8_t* gA = A + (size_t)sr * lda + scol;
  const uint8_t* gB = Bm + (size_t)sr * ldb + scol;
  uint8_t* b0 = lds;
  uint8_t* b1 = lds + 32768;

  #define STG(BUF, kt) do { \
    _Pragma("unroll") for (int i = 0; i < 4; i++) { \
      gld16b(gA + (size_t)(kt) * 128 + (size_t)i * 32 * lda, (BUF) + tid * 16 + i * 4096); \
      gld16b(gB + (size_t)(kt) * 128 + (size_t)i * 32 * ldb, (BUF) + 16384 + tid * 16 + i * 4096); \
    } } while (0)
  #define WAITB do { \
    asm volatile("s_waitcnt vmcnt(0) lgkmcnt(0)" ::: "memory"); \
    __builtin_amdgcn_s_barrier(); \
    __builtin_amdgcn_sched_barrier(0); } while (0)

  int NT = K >> 7;                 // 4 (gemmA/B) or 12 (gemmF) — always even
  STG(b0, 0);
  for (int t = 0; t < NT; t += 2) {
    WAITB;                         // tile t landed; everyone done reading b1
    STG(b1, t + 1);
    compute128(b0, b0 + 16384, wr, wc, lr, lk, acc);
    WAITB;                         // tile t+1 landed; everyone done reading b0
    if (t + 2 < NT) STG(b0, t + 2);
    compute128(b1, b1 + 16384, wr, wc, lr, lk, acc);
  }
  #undef STG
  #undef WAITB
}

// ---- kA (MX fp8): axpx = fp8x2( adj_hb @ X_{h,layer} + X )
__global__ __launch_bounds__(256, 2) void k_gemmA(
    const uint8_t* __restrict__ adjf8, const uint8_t* __restrict__ btp,
    const short* __restrict__ x0b, const uint8_t* __restrict__ finb,
    int layer, uint8_t* __restrict__ axpx) {
  extern __shared__ uint8_t lds[];
  int bx = xswz(HH*BB*16);
  int q = bx & 15;
  int g = bx >> 4;                 // b-major grouping: g = b*3 + h
  int b = g / 3, h = g - b * 3;
  int hb = h * BB + b;
  int tr = q >> 2, tc = q & 3;
  const uint8_t* A = adjf8 + (size_t)hb * SS * SS + (size_t)(tr * 128) * SS;
  const uint8_t* Bm = (layer == 0)
      ? btp + (size_t)b * DD * SS + (size_t)(tc * 128) * SS
      : btp + (size_t)hb * DD * SS + (size_t)(tc * 128) * SS;
  f32x4 acc[4][4];
  #pragma unroll
  for (int m = 0; m < 4; m++)
    #pragma unroll
    for (int n = 0; n < 4; n++) acc[m][n] = (f32x4){0.f, 0.f, 0.f, 0.f};
  gemmx8(A, SS, Bm, SS, SS, lds, acc);
  int lane = threadIdx.x & 63, wid = threadIdx.x >> 6;
  int wr = wid >> 1, wc = wid & 1;
  int r4 = (lane >> 4) * 4, cn = lane & 15;
  uint8_t* outp = axpx + (size_t)hb * SS * DD;
  #pragma unroll
  for (int m = 0; m < 4; m++) {
    #pragma unroll
    for (int n = 0; n < 4; n++) {
      int sb = tr*128 + wr*64 + m*16 + r4;
      int d = tc*128 + wc*64 + n*16 + cn;
      float vv[4];
      #pragma unroll
      for (int r = 0; r < 4; r++) {
        float v;
        if (layer == 0)
          v = acc[m][n][r] + b2f(x0b[((size_t)b * SS + sb + r) * DD + d]);
        else
          v = (acc[m][n][r] + c8(finb[((size_t)b * SS + sb + r) * FF + (size_t)(h * LL) * DD + d]))
              * 0.015625f;   // yt,finb carry x64 scale
        vv[r] = v * 2.0f;    // axpx carries x2 scale
      }
      uint32_t pk4 = 0;
      pk4 = __builtin_amdgcn_cvt_pk_fp8_f32(vv[0], vv[1], pk4, false);
      pk4 = __builtin_amdgcn_cvt_pk_fp8_f32(vv[2], vv[3], pk4, true);
      #pragma unroll
      for (int r = 0; r < 4; r++)
        outp[(size_t)(sb + r) * DD + d] = (uint8_t)(pk4 >> (8 * r));
    }
  }
}

// ---- kB (MX fp8): Y = relu((AxpX @ W^T + 2b) * rdenom) -> finb fp8(x64);
//      layer 0 also writes yt fp8(x64) transposed. acc scale /128.
__global__ __launch_bounds__(256, 2) void k_gemmB(
    const uint8_t* __restrict__ axpx, const uint8_t* __restrict__ wgb,
    const float* __restrict__ bg, const float* __restrict__ rden,
    int layer, uint8_t* __restrict__ finb, uint8_t* __restrict__ yt) {
  extern __shared__ uint8_t lds[];
  int bx = xswz(HH*BB*16);
  int hb = bx >> 4, q = bx & 15;
  int h = hb / BB, b = hb % BB;
  int tr = q >> 2, tc = q & 3;
  int idx = h * LL + layer;
  const uint8_t* A = axpx + (size_t)hb * SS * DD + (size_t)(tr * 128) * DD;
  const uint8_t* Bm = wgb + (size_t)idx * DD * DD + (size_t)(tc * 128) * DD;
  f32x4 acc[4][4];
  #pragma unroll
  for (int m = 0; m < 4; m++)
    #pragma unroll
    for (int n = 0; n < 4; n++) acc[m][n] = (f32x4){0.f, 0.f, 0.f, 0.f};
  gemmx8(A, DD, Bm, DD, DD, lds, acc);
  int lane = threadIdx.x & 63, wid = threadIdx.x >> 6;
  int wr = wid >> 1, wc = wid & 1;
  int r4 = (lane >> 4) * 4, cn = lane & 15;
  #pragma unroll
  for (int m = 0; m < 4; m++) {
    #pragma unroll
    for (int n = 0; n < 4; n++) {
      int sb = tr*128 + wr*64 + m*16 + r4;
      int e = tc*128 + wc*64 + n*16 + cn;
      float vv[4];
      #pragma unroll
      for (int r = 0; r < 4; r++) {
        float v = (acc[m][n][r] * 0.0078125f + 2.0f * bg[(size_t)idx * DD + e])
                  * rden[(size_t)hb * SS + sb + r];
        vv[r] = fmaxf(v, 0.0f) * 64.0f;
      }
      uint32_t pk4 = 0;
      pk4 = __builtin_amdgcn_cvt_pk_fp8_f32(vv[0], vv[1], pk4, false);
      pk4 = __builtin_amdgcn_cvt_pk_fp8_f32(vv[2], vv[3], pk4, true);
      #pragma unroll
      for (int r = 0; r < 4; r++)
        finb[((size_t)b * SS + sb + r) * FF + (size_t)idx * DD + e] =
            (uint8_t)(pk4 >> (8 * r));
      if (layer == 0)
        *(uint32_t*)(yt + (size_t)hb * DD * SS + (size_t)e * SS + sb) = pk4;
    }
  }
}

// ---- kF (MX fp8, split-K=2): part[ks] = finb[:, ks*1536+..] @ wob[:, same]^T / 4096
__global__ __launch_bounds__(256, 2) void k_gemmF(
    const uint8_t* __restrict__ finb, const uint8_t* __restrict__ wob,
    short* __restrict__ part) {
  extern __shared__ uint8_t lds[];
  int bx = xswz(BB*16*2);          // 512 blocks
  int ks = bx >> 8;                // 0..1
  int q = bx & 255;
  int tr = q >> 2, tc = q & 3;     // tr 0..63, tc 0..3
  const uint8_t* A = finb + (size_t)(tr * 128) * FF + ks * 1536;
  const uint8_t* Bm = wob + (size_t)(tc * 128) * FF + ks * 1536;
  f32x4 acc[4][4];
  #pragma unroll
  for (int m = 0; m < 4; m++)
    #pragma unroll
    for (int n = 0; n < 4; n++) acc[m][n] = (f32x4){0.f, 0.f, 0.f, 0.f};
  gemmx8(A, FF, Bm, FF, 1536, lds, acc);
  int lane = threadIdx.x & 63, wid = threadIdx.x >> 6;
  int wr = wid >> 1, wc = wid & 1;
  int r4 = (lane >> 4) * 4, cn = lane & 15;
  short* op = part + (size_t)ks * ((size_t)BB*SS*DD);
  #pragma unroll
  for (int m = 0; m < 4; m++) {
    #pragma unroll
    for (int n = 0; n < 4; n++) {
      #pragma unroll
      for (int r = 0; r < 4; r++) {
        int row = tr*128 + wr*64 + m*16 + r4 + r;
        int d = tc*128 + wc*64 + n*16 + cn;
        op[(size_t)row * DD + d] = f2b(acc[m][n][r] * (1.0f / 4096.0f));
      }
    }
  }
}

// ---- reduce: out = x0 + b_out + part0 + part1   (bf16 parts, 8/thread)
__global__ void k_redF(const short* __restrict__ part, const float* __restrict__ x0f,
                       const float* __restrict__ bo, float* __restrict__ out) {
  const size_t PSZ = (size_t)BB * SS * DD;          // 4,194,304
  size_t i = ((size_t)blockIdx.x * 256 + threadIdx.x) * 8;
  if (i >= PSZ) return;
  int d = (int)(i & (DD - 1));
  bf16x8 q0 = *(const bf16x8*)(part + i);
  bf16x8 q1 = *(const bf16x8*)(part + PSZ + i);
  vfloat4 xa = *(const vfloat4*)(x0f + i);
  vfloat4 xb = *(const vfloat4*)(x0f + i + 4);
  vfloat4 ba = *(const vfloat4*)(bo + d);
  vfloat4 bb = *(const vfloat4*)(bo + d + 4);
  vfloat4 oa, ob;
  #pragma unroll
  for (int j = 0; j < 4; j++) {
    oa[j] = b2f(q0[j]) + b2f(q1[j]) + xa[j] + ba[j];
    ob[j] = b2f(q0[j+4]) + b2f(q1[j+4]) + xb[j] + bb[j];
  }
  *(vfloat4*)(out + i) = oa;
  *(vfloat4*)(out + i + 4) = ob;
}

extern "C" void kernel_launch(void* const* d_in, const int* in_sizes, int n_in,
                              void* d_out, int out_size, void* d_ws, size_t ws_size,
                              hipStream_t stream) {
  const float* adj = (const float*)d_in[0];
  const float* x0  = (const float*)d_in[1];
  // d_in[2], d_in[3]: mask / domain_mask — unused by the reference forward.
  const float* wg  = (const float*)d_in[4];
  const float* bg  = (const float*)d_in[5];
  const float* wo  = (const float*)d_in[6];
  const float* bo  = (const float*)d_in[7];
  float* out = (float*)d_out;

  char* p = (char*)d_ws;
  uint8_t* adjf8 = (uint8_t*)p; p += (size_t)HH*BB*SS*SS;   // 12,582,912
  uint8_t* x0t   = (uint8_t*)p; p += (size_t)BB*DD*SS;      //  4,194,304
  uint8_t* yt    = (uint8_t*)p; p += (size_t)HH*BB*DD*SS;   // 12,582,912
  uint8_t* axpx  = (uint8_t*)p; p += (size_t)HH*BB*SS*DD;   // 12,582,912
  uint8_t* finb  = (uint8_t*)p; p += (size_t)BB*SS*FF;      // 25,165,824
  uint8_t* wgb   = (uint8_t*)p; p += (size_t)HH*LL*DD*DD;   //  1,572,864
  uint8_t* wob   = (uint8_t*)p; p += (size_t)DD*FF;         //  1,572,864
  float*   rden  = (float*)p;   p += (size_t)HH*BB*SS*4;    //     98,304
  short*   x0b   = (short*)p;   p += (size_t)BB*SS*DD*2;    //  8,388,608
  // total ~78.7 MiB. split-K=2 bf16 parts (16.8 MB) overlay adjf8+x0t
  // (16.8 MB exactly) — both dead by gemmF time.
  short* part = (short*)d_ws;

  hipFuncSetAttribute((const void*)k_gemmA,
                      hipFuncAttributeMaxDynamicSharedMemorySize, 65536);
  hipFuncSetAttribute((const void*)k_gemmB,
                      hipFuncAttributeMaxDynamicSharedMemorySize, 65536);
  hipFuncSetAttribute((const void*)k_gemmF,
                      hipFuncAttributeMaxDynamicSharedMemorySize, 65536);

  // prep: adj->fp8 + rden | W->fp8 | x0 transpose+cvt, one dispatch
  k_prep<<<6144 + 768 + BB*64, 256, 0, stream>>>(
      adj, adjf8, rden, wg, wo, wgb, wob, x0, x0t, x0b);

  // layer 0
  k_gemmA<<<HH*BB*16, 256, 65536, stream>>>(adjf8, x0t, x0b, finb, 0, axpx);
  k_gemmB<<<HH*BB*16, 256, 65536, stream>>>(axpx, wgb, bg, rden, 0, finb, yt);
  // layer 1 (gemmB layer-0 epilogue wrote yt = transposed fp8 x64 outputs)
  k_gemmA<<<HH*BB*16, 256, 65536, stream>>>(adjf8, yt, x0b, finb, 1, axpx);
  k_gemmB<<<HH*BB*16, 256, 65536, stream>>>(axpx, wgb, bg, rden, 1, finb, yt);
  // output projection (MX fp8, split-K=2) + fused reduce w/ bias + residual
  k_gemmF<<<BB*16*2, 256, 65536, stream>>>(finb, wob, part);
  k_redF<<<2048, 256, 0, stream>>>(part, x0, bo, out);
}

// Round 12
// 139.480 us; speedup vs baseline: 1.4511x; 1.4511x over previous
//
#include <hip/hip_runtime.h>
#include <hip/hip_bf16.h>
#include <stdint.h>

// MultiGraphConvLayer: H=3 heads, L=2 layers, B=16, S=512, D=512.
// Round 12: R10 fp8 pipeline with BK=64 / 3-buffer GEMM core (32 MFMA per
// barrier, lead-2, vmcnt(4), 48KB LDS, sigma(r)=(r^(r>>2))&3 slot swizzle).
// Numerics identical to R10 (scales: y,w x64; axpx x2).

#define HH 3
#define LL 2
#define BB 16
#define SS 512
#define DD 512
#define FF 3072  // HH*LL*DD

typedef __attribute__((ext_vector_type(8))) short bf16x8;
typedef __attribute__((ext_vector_type(4))) float f32x4;
typedef __attribute__((ext_vector_type(4))) float vfloat4;
typedef __attribute__((ext_vector_type(4))) short shortx4;
typedef __attribute__((ext_vector_type(2))) unsigned int uint2v;

__device__ __forceinline__ short f2b(float x) {
  union { float f; uint32_t u; } v; v.f = x;
  return (short)((v.u + 0x7FFFu + ((v.u >> 16) & 1u)) >> 16);
}
__device__ __forceinline__ float b2f(short s) {
  union { uint32_t u; float f; } v; v.u = ((uint32_t)(uint16_t)s) << 16;
  return v.f;
}
__device__ __forceinline__ float c8(uint8_t b) {
  return __builtin_amdgcn_cvt_f32_fp8((int)b, 0);
}

__device__ __forceinline__ void gld16b(const uint8_t* g, uint8_t* l) {
  __builtin_amdgcn_global_load_lds((const __attribute__((address_space(1))) void*)g,
                                   (__attribute__((address_space(3))) void*)l, 16, 0, 0);
}

// T1: XCD-chunked blockIdx swizzle (grid divisible by 8 — all ours are).
__device__ __forceinline__ int xswz(int grid) {
  int cpx = grid >> 3;
  return (blockIdx.x & 7) * cpx + (blockIdx.x >> 3);
}

// ---- merged prep: [0,6144) adj->fp8 + rden; [6144,6912) W->fp8 x64;
//      [6912,7936) x0 -> X0T fp8 + x0b bf16.
__global__ void k_prep(const float* __restrict__ adj, uint8_t* __restrict__ adjf8,
                       float* __restrict__ rden,
                       const float* __restrict__ wg, const float* __restrict__ wo,
                       uint8_t* __restrict__ wgb, uint8_t* __restrict__ wob,
                       const float* __restrict__ x, uint8_t* __restrict__ xt,
                       short* __restrict__ x0b) {
  __shared__ short t[64][72];
  int bid = blockIdx.x;
  int tid = threadIdx.x;
  if (bid < 6144) {
    int row = bid * 4 + (tid >> 6);
    int lane = tid & 63;
    const float* src = adj + (size_t)row * SS;
    vfloat4 a = *(const vfloat4*)(src + lane * 8);
    vfloat4 b = *(const vfloat4*)(src + lane * 8 + 4);
    uint32_t w0 = 0, w1 = 0;
    w0 = __builtin_amdgcn_cvt_pk_fp8_f32(a[0], a[1], w0, false);
    w0 = __builtin_amdgcn_cvt_pk_fp8_f32(a[2], a[3], w0, true);
    w1 = __builtin_amdgcn_cvt_pk_fp8_f32(b[0], b[1], w1, false);
    w1 = __builtin_amdgcn_cvt_pk_fp8_f32(b[2], b[3], w1, true);
    uint2v o; o[0] = w0; o[1] = w1;
    *(uint2v*)(adjf8 + (size_t)row * SS + lane * 8) = o;
    float s = a[0]+a[1]+a[2]+a[3]+b[0]+b[1]+b[2]+b[3];
    #pragma unroll
    for (int off = 32; off > 0; off >>= 1) s += __shfl_xor(s, off);
    if (lane == 0) rden[row] = 1.0f / (s + 1.0f);
  } else if (bid < 6912) {
    size_t i = ((size_t)(bid - 6144) * 256 + tid) * 8;
    vfloat4 a = *(const vfloat4*)(wg + i);
    vfloat4 b = *(const vfloat4*)(wg + i + 4);
    uint32_t w0 = 0, w1 = 0;
    w0 = __builtin_amdgcn_cvt_pk_fp8_f32(a[0]*64.f, a[1]*64.f, w0, false);
    w0 = __builtin_amdgcn_cvt_pk_fp8_f32(a[2]*64.f, a[3]*64.f, w0, true);
    w1 = __builtin_amdgcn_cvt_pk_fp8_f32(b[0]*64.f, b[1]*64.f, w1, false);
    w1 = __builtin_amdgcn_cvt_pk_fp8_f32(b[2]*64.f, b[3]*64.f, w1, true);
    uint2v o; o[0] = w0; o[1] = w1;
    *(uint2v*)(wgb + i) = o;
    a = *(const vfloat4*)(wo + i);
    b = *(const vfloat4*)(wo + i + 4);
    w0 = 0; w1 = 0;
    w0 = __builtin_amdgcn_cvt_pk_fp8_f32(a[0]*64.f, a[1]*64.f, w0, false);
    w0 = __builtin_amdgcn_cvt_pk_fp8_f32(a[2]*64.f, a[3]*64.f, w0, true);
    w1 = __builtin_amdgcn_cvt_pk_fp8_f32(b[0]*64.f, b[1]*64.f, w1, false);
    w1 = __builtin_amdgcn_cvt_pk_fp8_f32(b[2]*64.f, b[3]*64.f, w1, true);
    o[0] = w0; o[1] = w1;
    *(uint2v*)(wob + i) = o;
  } else {
    int bid2 = bid - 6912;           // BB*64
    int b = bid2 >> 6, q = bid2 & 63;
    int s0 = (q >> 3) * 64, d0 = (q & 7) * 64;
    int r = tid >> 4, c4 = (tid & 15) * 4;
    const float* src = x + ((size_t)b * SS + s0) * DD + d0;
    #pragma unroll
    for (int rr = 0; rr < 64; rr += 16) {
      vfloat4 v = *(const vfloat4*)(src + (size_t)(r + rr) * DD + c4);
      shortx4 o4;
      o4[0] = f2b(v[0]); o4[1] = f2b(v[1]); o4[2] = f2b(v[2]); o4[3] = f2b(v[3]);
      t[r+rr][c4+0] = o4[0]; t[r+rr][c4+1] = o4[1];
      t[r+rr][c4+2] = o4[2]; t[r+rr][c4+3] = o4[3];
      *(shortx4*)(x0b + ((size_t)b * SS + s0 + r + rr) * DD + d0 + c4) = o4;
    }
    __syncthreads();
    int dloc = tid >> 3, s8 = (tid & 7) * 8;
    uint8_t* dst = xt + (size_t)b * DD * SS + s0;
    #pragma unroll
    for (int dd = 0; dd < 64; dd += 32) {
      float f[8];
      #pragma unroll
      for (int j = 0; j < 8; j++) f[j] = b2f(t[s8 + j][dloc + dd]);
      uint32_t w0 = 0, w1 = 0;
      w0 = __builtin_amdgcn_cvt_pk_fp8_f32(f[0], f[1], w0, false);
      w0 = __builtin_amdgcn_cvt_pk_fp8_f32(f[2], f[3], w0, true);
      w1 = __builtin_amdgcn_cvt_pk_fp8_f32(f[4], f[5], w1, false);
      w1 = __builtin_amdgcn_cvt_pk_fp8_f32(f[6], f[7], w1, true);
      uint2v o; o[0] = w0; o[1] = w1;
      *(uint2v*)(dst + (size_t)(d0 + dloc + dd) * SS + s8) = o;
    }
  }
}

// ======================= fp8 GEMM core, BK=64 / 3-buffer =======================
// C(128x128) = A(128xK fp8, lda bytes) * B'(128xK fp8, ldb bytes)^T.
// 4 waves, 64x64 each; 2x mfma_f32_16x16x32_fp8_fp8 sweeps per K-step (BK=64).
// LDS: 3 bufs x (A [128][64B] | B [128][64B]) = 48KB -> 3 blocks/CU (= grid).
// Stage: thread (sr=tid>>2, ss=tid&3) -> LDS linear tid*16; source slot
// permuted ss^sigma(sr), sigma(r)=(r^(r>>2))&3 (involution; sigma(r+64)=sigma(r);
// read-side 2-way banks = free). Lead-2, 8 loads in flight, steady vmcnt(4).
__device__ __forceinline__ void compute64f8(const uint8_t* As, const uint8_t* Bs,
                                            int wr, int wc, int lr, int lk,
                                            int sx, f32x4 acc[4][4]) {
  #pragma unroll
  for (int h = 0; h < 2; h++) {
    int slot = ((((h << 1) + (lk >> 1)) ^ sx) << 4) + (lk & 1) * 8;
    long af[4], bv[4];
    #pragma unroll
    for (int m = 0; m < 4; m++)
      af[m] = *(const long*)(As + (size_t)(wr*64 + m*16 + lr) * 64 + slot);
    #pragma unroll
    for (int n = 0; n < 4; n++)
      bv[n] = *(const long*)(Bs + (size_t)(wc*64 + n*16 + lr) * 64 + slot);
    #pragma unroll
    for (int m = 0; m < 4; m++)
      #pragma unroll
      for (int n = 0; n < 4; n++)
        acc[m][n] = __builtin_amdgcn_mfma_f32_16x16x32_fp8_fp8(af[m], bv[n], acc[m][n], 0, 0, 0);
  }
}

__device__ __forceinline__ void gemmf8(const uint8_t* __restrict__ A, int lda,
                                       const uint8_t* __restrict__ Bm, int ldb,
                                       int K, uint8_t* lds, f32x4 acc[4][4]) {
  int tid = threadIdx.x;
  int lane = tid & 63, wid = tid >> 6;
  int wr = wid >> 1, wc = wid & 1;
  int lr = lane & 15, lk = lane >> 4;
  int sx = (lr ^ (lr >> 2)) & 3;
  int sr = tid >> 2, ss = tid & 3;
  int gc = ((ss ^ ((sr ^ (sr >> 2)) & 3)) << 4);
  const uint8_t* gA = A + (size_t)sr * lda + gc;
  const uint8_t* gB = Bm + (size_t)sr * ldb + gc;

  #define STG(BUF, kt) do { \
    gld16b(gA + (size_t)(kt) * 64,                        (BUF) + tid * 16); \
    gld16b(gA + (size_t)(kt) * 64 + (size_t)64 * lda,     (BUF) + 4096 + tid * 16); \
    gld16b(gB + (size_t)(kt) * 64,                        (BUF) + 8192 + tid * 16); \
    gld16b(gB + (size_t)(kt) * 64 + (size_t)64 * ldb,     (BUF) + 12288 + tid * 16); \
  } while (0)
  #define STEPW(VM) do { \
    asm volatile("s_waitcnt vmcnt(" #VM ")" ::: "memory"); \
    __builtin_amdgcn_s_barrier(); \
    __builtin_amdgcn_sched_barrier(0); } while (0)
  #define ROT3 do { uint8_t* t_ = p0; p0 = p1; p1 = p2; p2 = t_; } while (0)

  uint8_t* p0 = lds;
  uint8_t* p1 = lds + 16384;
  uint8_t* p2 = lds + 32768;
  int NT = K >> 6;                 // 8 (gemmA/B) or 24 (gemmF)
  STG(p0, 0);
  STG(p1, 1);
  for (int t = 0; t < NT - 2; t++) {
    STEPW(4);
    STG(p2, t + 2);
    compute64f8(p0, p0 + 8192, wr, wc, lr, lk, sx, acc);
    ROT3;
  }
  STEPW(4); compute64f8(p0, p0 + 8192, wr, wc, lr, lk, sx, acc); ROT3;
  STEPW(0); compute64f8(p0, p0 + 8192, wr, wc, lr, lk, sx, acc);
  #undef STG
  #undef STEPW
  #undef ROT3
}

// ---- kA (fp8): axpx = fp8x2( adj_hb @ X_{h,layer} + X )
__global__ __launch_bounds__(256, 3) void k_gemmA(
    const uint8_t* __restrict__ adjf8, const uint8_t* __restrict__ btp,
    const short* __restrict__ x0b, const uint8_t* __restrict__ finb,
    int layer, uint8_t* __restrict__ axpx) {
  __shared__ uint8_t lds[49152];
  int bx = xswz(HH*BB*16);
  int q = bx & 15;
  int g = bx >> 4;                 // b-major grouping: g = b*3 + h
  int b = g / 3, h = g - b * 3;
  int hb = h * BB + b;
  int tr = q >> 2, tc = q & 3;
  const uint8_t* A = adjf8 + (size_t)hb * SS * SS + (size_t)(tr * 128) * SS;
  const uint8_t* Bm = (layer == 0)
      ? btp + (size_t)b * DD * SS + (size_t)(tc * 128) * SS
      : btp + (size_t)hb * DD * SS + (size_t)(tc * 128) * SS;
  f32x4 acc[4][4];
  #pragma unroll
  for (int m = 0; m < 4; m++)
    #pragma unroll
    for (int n = 0; n < 4; n++) acc[m][n] = (f32x4){0.f, 0.f, 0.f, 0.f};
  gemmf8(A, SS, Bm, SS, SS, lds, acc);
  int lane = threadIdx.x & 63, wid = threadIdx.x >> 6;
  int wr = wid >> 1, wc = wid & 1;
  int r4 = (lane >> 4) * 4, cn = lane & 15;
  uint8_t* outp = axpx + (size_t)hb * SS * DD;
  #pragma unroll
  for (int m = 0; m < 4; m++) {
    #pragma unroll
    for (int n = 0; n < 4; n++) {
      int sb = tr*128 + wr*64 + m*16 + r4;
      int d = tc*128 + wc*64 + n*16 + cn;
      float vv[4];
      #pragma unroll
      for (int r = 0; r < 4; r++) {
        float v;
        if (layer == 0)
          v = acc[m][n][r] + b2f(x0b[((size_t)b * SS + sb + r) * DD + d]);
        else
          v = (acc[m][n][r] + c8(finb[((size_t)b * SS + sb + r) * FF + (size_t)(h * LL) * DD + d]))
              * 0.015625f;   // yt,finb carry x64 scale
        vv[r] = v * 2.0f;    // axpx carries x2 scale
      }
      uint32_t pk4 = 0;
      pk4 = __builtin_amdgcn_cvt_pk_fp8_f32(vv[0], vv[1], pk4, false);
      pk4 = __builtin_amdgcn_cvt_pk_fp8_f32(vv[2], vv[3], pk4, true);
      #pragma unroll
      for (int r = 0; r < 4; r++)
        outp[(size_t)(sb + r) * DD + d] = (uint8_t)(pk4 >> (8 * r));
    }
  }
}

// ---- kB (fp8): Y = relu((AxpX @ W^T + 2b) * rdenom) -> finb fp8(x64);
//      layer 0 also writes yt fp8(x64) transposed. acc scale /128.
__global__ __launch_bounds__(256, 3) void k_gemmB(
    const uint8_t* __restrict__ axpx, const uint8_t* __restrict__ wgb,
    const float* __restrict__ bg, const float* __restrict__ rden,
    int layer, uint8_t* __restrict__ finb, uint8_t* __restrict__ yt) {
  __shared__ uint8_t lds[49152];
  int bx = xswz(HH*BB*16);
  int hb = bx >> 4, q = bx & 15;
  int h = hb / BB, b = hb % BB;
  int tr = q >> 2, tc = q & 3;
  int idx = h * LL + layer;
  const uint8_t* A = axpx + (size_t)hb * SS * DD + (size_t)(tr * 128) * DD;
  const uint8_t* Bm = wgb + (size_t)idx * DD * DD + (size_t)(tc * 128) * DD;
  f32x4 acc[4][4];
  #pragma unroll
  for (int m = 0; m < 4; m++)
    #pragma unroll
    for (int n = 0; n < 4; n++) acc[m][n] = (f32x4){0.f, 0.f, 0.f, 0.f};
  gemmf8(A, DD, Bm, DD, DD, lds, acc);
  int lane = threadIdx.x & 63, wid = threadIdx.x >> 6;
  int wr = wid >> 1, wc = wid & 1;
  int r4 = (lane >> 4) * 4, cn = lane & 15;
  #pragma unroll
  for (int m = 0; m < 4; m++) {
    #pragma unroll
    for (int n = 0; n < 4; n++) {
      int sb = tr*128 + wr*64 + m*16 + r4;
      int e = tc*128 + wc*64 + n*16 + cn;
      float vv[4];
      #pragma unroll
      for (int r = 0; r < 4; r++) {
        float v = (acc[m][n][r] * 0.0078125f + 2.0f * bg[(size_t)idx * DD + e])
                  * rden[(size_t)hb * SS + sb + r];
        vv[r] = fmaxf(v, 0.0f) * 64.0f;
      }
      uint32_t pk4 = 0;
      pk4 = __builtin_amdgcn_cvt_pk_fp8_f32(vv[0], vv[1], pk4, false);
      pk4 = __builtin_amdgcn_cvt_pk_fp8_f32(vv[2], vv[3], pk4, true);
      #pragma unroll
      for (int r = 0; r < 4; r++)
        finb[((size_t)b * SS + sb + r) * FF + (size_t)idx * DD + e] =
            (uint8_t)(pk4 >> (8 * r));
      if (layer == 0)
        *(uint32_t*)(yt + (size_t)hb * DD * SS + (size_t)e * SS + sb) = pk4;
    }
  }
}

// ---- kF (fp8, split-K=2): part[ks] = finb[:, ks*1536+..] @ wob[:, same]^T / 4096
__global__ __launch_bounds__(256, 3) void k_gemmF(
    const uint8_t* __restrict__ finb, const uint8_t* __restrict__ wob,
    short* __restrict__ part) {
  __shared__ uint8_t lds[49152];
  int bx = xswz(BB*16*2);          // 512 blocks
  int ks = bx >> 8;                // 0..1
  int q = bx & 255;
  int tr = q >> 2, tc = q & 3;     // tr 0..63, tc 0..3
  const uint8_t* A = finb + (size_t)(tr * 128) * FF + ks * 1536;
  const uint8_t* Bm = wob + (size_t)(tc * 128) * FF + ks * 1536;
  f32x4 acc[4][4];
  #pragma unroll
  for (int m = 0; m < 4; m++)
    #pragma unroll
    for (int n = 0; n < 4; n++) acc[m][n] = (f32x4){0.f, 0.f, 0.f, 0.f};
  gemmf8(A, FF, Bm, FF, 1536, lds, acc);
  int lane = threadIdx.x & 63, wid = threadIdx.x >> 6;
  int wr = wid >> 1, wc = wid & 1;
  int r4 = (lane >> 4) * 4, cn = lane & 15;
  short* op = part + (size_t)ks * ((size_t)BB*SS*DD);
  #pragma unroll
  for (int m = 0; m < 4; m++) {
    #pragma unroll
    for (int n = 0; n < 4; n++) {
      #pragma unroll
      for (int r = 0; r < 4; r++) {
        int row = tr*128 + wr*64 + m*16 + r4 + r;
        int d = tc*128 + wc*64 + n*16 + cn;
        op[(size_t)row * DD + d] = f2b(acc[m][n][r] * (1.0f / 4096.0f));
      }
    }
  }
}

// ---- reduce: out = x0 + b_out + part0 + part1   (bf16 parts, 8/thread)
__global__ void k_redF(const short* __restrict__ part, const float* __restrict__ x0f,
                       const float* __restrict__ bo, float* __restrict__ out) {
  const size_t PSZ = (size_t)BB * SS * DD;          // 4,194,304
  size_t i = ((size_t)blockIdx.x * 256 + threadIdx.x) * 8;
  if (i >= PSZ) return;
  int d = (int)(i & (DD - 1));
  bf16x8 q0 = *(const bf16x8*)(part + i);
  bf16x8 q1 = *(const bf16x8*)(part + PSZ + i);
  vfloat4 xa = *(const vfloat4*)(x0f + i);
  vfloat4 xb = *(const vfloat4*)(x0f + i + 4);
  vfloat4 ba = *(const vfloat4*)(bo + d);
  vfloat4 bb = *(const vfloat4*)(bo + d + 4);
  vfloat4 oa, ob;
  #pragma unroll
  for (int j = 0; j < 4; j++) {
    oa[j] = b2f(q0[j]) + b2f(q1[j]) + xa[j] + ba[j];
    ob[j] = b2f(q0[j+4]) + b2f(q1[j+4]) + xb[j] + bb[j];
  }
  *(vfloat4*)(out + i) = oa;
  *(vfloat4*)(out + i + 4) = ob;
}

extern "C" void kernel_launch(void* const* d_in, const int* in_sizes, int n_in,
                              void* d_out, int out_size, void* d_ws, size_t ws_size,
                              hipStream_t stream) {
  const float* adj = (const float*)d_in[0];
  const float* x0  = (const float*)d_in[1];
  // d_in[2], d_in[3]: mask / domain_mask — unused by the reference forward.
  const float* wg  = (const float*)d_in[4];
  const float* bg  = (const float*)d_in[5];
  const float* wo  = (const float*)d_in[6];
  const float* bo  = (const float*)d_in[7];
  float* out = (float*)d_out;

  char* p = (char*)d_ws;
  uint8_t* adjf8 = (uint8_t*)p; p += (size_t)HH*BB*SS*SS;   // 12,582,912
  uint8_t* x0t   = (uint8_t*)p; p += (size_t)BB*DD*SS;      //  4,194,304
  uint8_t* yt    = (uint8_t*)p; p += (size_t)HH*BB*DD*SS;   // 12,582,912
  uint8_t* axpx  = (uint8_t*)p; p += (size_t)HH*BB*SS*DD;   // 12,582,912
  uint8_t* finb  = (uint8_t*)p; p += (size_t)BB*SS*FF;      // 25,165,824
  uint8_t* wgb   = (uint8_t*)p; p += (size_t)HH*LL*DD*DD;   //  1,572,864
  uint8_t* wob   = (uint8_t*)p; p += (size_t)DD*FF;         //  1,572,864
  float*   rden  = (float*)p;   p += (size_t)HH*BB*SS*4;    //     98,304
  short*   x0b   = (short*)p;   p += (size_t)BB*SS*DD*2;    //  8,388,608
  // total ~78.7 MiB. split-K=2 bf16 parts (16.8 MB) overlay adjf8+x0t
  // (16.8 MB exactly) — both dead by gemmF time.
  short* part = (short*)d_ws;

  // prep: adj->fp8 + rden | W->fp8 | x0 transpose+cvt, one dispatch
  k_prep<<<6144 + 768 + BB*64, 256, 0, stream>>>(
      adj, adjf8, rden, wg, wo, wgb, wob, x0, x0t, x0b);

  // layer 0
  k_gemmA<<<HH*BB*16, 256, 0, stream>>>(adjf8, x0t, x0b, finb, 0, axpx);
  k_gemmB<<<HH*BB*16, 256, 0, stream>>>(axpx, wgb, bg, rden, 0, finb, yt);
  // layer 1 (gemmB layer-0 epilogue wrote yt = transposed fp8 x64 outputs)
  k_gemmA<<<HH*BB*16, 256, 0, stream>>>(adjf8, yt, x0b, finb, 1, axpx);
  k_gemmB<<<HH*BB*16, 256, 0, stream>>>(axpx, wgb, bg, rden, 1, finb, yt);
  // output projection (fp8, split-K=2) + fused reduce w/ bias + residual
  k_gemmF<<<BB*16*2, 256, 0, stream>>>(finb, wob, part);
  k_redF<<<2048, 256, 0, stream>>>(part, x0, bo, out);
}